// Round 1
// baseline (670.284 us; speedup 1.0000x reference)
//
#include <hip/hip_runtime.h>
#include <math.h>

#define N_ROWS 4096
#define DIM    256
#define P_SZ   5532
#define Q_SZ   5000
#define C_COLS (P_SZ + Q_SZ)   // 10532
#define K_SEL  701              // HARD_NUM + 1
#define SCALAR 30.0f

#define BM 64
#define BN 64
#define BK 16

// ---------------- GEMM: proj[n][c] = dot(inputs[n], table[c]) * rel[c] ----------------
__global__ __launch_bounds__(256) void gemm_proj(
    const float* __restrict__ inputs, const float* __restrict__ lut,
    const float* __restrict__ cq, const float* __restrict__ rel,
    float* __restrict__ proj)
{
    // k-major LDS tiles so the inner loop does float4 reads along M/N
    __shared__ float As[BK][BM + 4];
    __shared__ float Bs[BK][BN + 4];

    const int tid = threadIdx.x;
    const int tx = tid % 16, ty = tid / 16;   // 16x16 threads, 4x4 outputs each
    const int row0 = blockIdx.y * BM;
    const int col0 = blockIdx.x * BN;

    float acc[4][4] = {};

    for (int k0 = 0; k0 < DIM; k0 += BK) {
        // stage A: 64x16 = 1024 floats, one float4 per thread
        {
            int r = tid / 4;              // 0..63
            int c = (tid % 4) * 4;        // 0,4,8,12
            const float4 v = *reinterpret_cast<const float4*>(
                &inputs[(size_t)(row0 + r) * DIM + k0 + c]);
            As[c + 0][r] = v.x; As[c + 1][r] = v.y;
            As[c + 2][r] = v.z; As[c + 3][r] = v.w;
        }
        // stage B (table = [lut; cq] selected per row)
        {
            int r = tid / 4;
            int c = (tid % 4) * 4;
            int gc = col0 + r;
            float4 v = make_float4(0.f, 0.f, 0.f, 0.f);
            if (gc < C_COLS) {
                const float* src = (gc < P_SZ) ? (lut + (size_t)gc * DIM)
                                               : (cq + (size_t)(gc - P_SZ) * DIM);
                v = *reinterpret_cast<const float4*>(&src[k0 + c]);
            }
            Bs[c + 0][r] = v.x; Bs[c + 1][r] = v.y;
            Bs[c + 2][r] = v.z; Bs[c + 3][r] = v.w;
        }
        __syncthreads();

        #pragma unroll
        for (int kk = 0; kk < BK; ++kk) {
            const float4 a = *reinterpret_cast<const float4*>(&As[kk][ty * 4]);
            const float4 b = *reinterpret_cast<const float4*>(&Bs[kk][tx * 4]);
            const float av[4] = {a.x, a.y, a.z, a.w};
            const float bv[4] = {b.x, b.y, b.z, b.w};
            #pragma unroll
            for (int i = 0; i < 4; ++i)
                #pragma unroll
                for (int j = 0; j < 4; ++j)
                    acc[i][j] = fmaf(av[i], bv[j], acc[i][j]);
        }
        __syncthreads();
    }

    #pragma unroll
    for (int i = 0; i < 4; ++i) {
        const int r = row0 + ty * 4 + i;
        #pragma unroll
        for (int j = 0; j < 4; ++j) {
            const int c = col0 + tx * 4 + j;
            if (c < C_COLS)
                proj[(size_t)r * C_COLS + c] = acc[i][j] * rel[c];
        }
    }
}

// ---------------- per-row: radix-select 701st largest + masked logsumexp ----------------
__device__ __forceinline__ unsigned int f2key(float f) {
    unsigned int b = __float_as_uint(f);
    return (b & 0x80000000u) ? ~b : (b | 0x80000000u);
}

__global__ __launch_bounds__(256) void row_loss_kernel(
    const float* __restrict__ proj, const int* __restrict__ labels,
    float* __restrict__ row_loss)
{
    __shared__ float vals[C_COLS];          // 42128 B — whole row in LDS
    __shared__ unsigned int hist[256];
    __shared__ float red[256];
    __shared__ unsigned int sel_bucket, sel_k;

    const int row = blockIdx.x;
    const int tid = threadIdx.x;
    const float* prow = proj + (size_t)row * C_COLS;

    for (int i = tid; i < C_COLS; i += 256) vals[i] = prow[i];
    __syncthreads();

    // radix select: find key of the K_SEL-th largest value (8 bits x 4 passes)
    unsigned int prefix = 0;
    unsigned int k = K_SEL;
    for (int pass = 0; pass < 4; ++pass) {
        const int shift = 24 - 8 * pass;
        hist[tid] = 0;
        __syncthreads();
        for (int i = tid; i < C_COLS; i += 256) {
            unsigned int key = f2key(vals[i]);
            if (pass == 0 || (key >> (shift + 8)) == prefix)
                atomicAdd(&hist[(key >> shift) & 0xFFu], 1u);
        }
        __syncthreads();
        if (tid == 0) {
            unsigned int cum = 0;
            for (int b = 255; b >= 0; --b) {
                unsigned int c = hist[b];
                if (cum + c >= k) { sel_bucket = (unsigned int)b; sel_k = k - cum; break; }
                cum += c;
            }
        }
        __syncthreads();
        prefix = (prefix << 8) | sel_bucket;
        k = sel_k;
        __syncthreads();
    }
    // invert key -> boundary float
    const unsigned int bbits = (prefix & 0x80000000u) ? (prefix & 0x7FFFFFFFu) : ~prefix;
    const float boundary = __uint_as_float(bbits);

    // row max (stabilizer; the max is always inside the masked set)
    float m = -INFINITY;
    for (int i = tid; i < C_COLS; i += 256) m = fmaxf(m, vals[i]);
    red[tid] = m; __syncthreads();
    for (int s = 128; s > 0; s >>= 1) {
        if (tid < s) red[tid] = fmaxf(red[tid], red[tid + s]);
        __syncthreads();
    }
    m = red[0];
    __syncthreads();

    // sum of exp over masked entries
    float s = 0.f;
    for (int i = tid; i < C_COLS; i += 256) {
        const float v = vals[i];
        if (v >= boundary) s += expf(SCALAR * (v - m));
    }
    red[tid] = s; __syncthreads();
    for (int t = 128; t > 0; t >>= 1) {
        if (tid < t) red[tid] += red[tid + t];
        __syncthreads();
    }

    if (tid == 0) {
        const int label = labels[row];
        const float plabel = vals[label];   // label < P always
        float total = red[0];
        if (plabel < boundary) total += expf(SCALAR * (plabel - m));  // label always unmasked
        const float logZ = SCALAR * m + logf(total);
        row_loss[row] = logZ - SCALAR * plabel;
    }
}

// ---------------- final mean ----------------
__global__ __launch_bounds__(256) void final_reduce(
    const float* __restrict__ row_loss, float* __restrict__ out)
{
    __shared__ float red[256];
    const int tid = threadIdx.x;
    float s = 0.f;
    for (int i = tid; i < N_ROWS; i += 256) s += row_loss[i];
    red[tid] = s; __syncthreads();
    for (int t = 128; t > 0; t >>= 1) {
        if (tid < t) red[tid] += red[tid + t];
        __syncthreads();
    }
    if (tid == 0) out[0] = red[0] / (float)N_ROWS;
}

extern "C" void kernel_launch(void* const* d_in, const int* in_sizes, int n_in,
                              void* d_out, int out_size, void* d_ws, size_t ws_size,
                              hipStream_t stream) {
    const float* inputs = (const float*)d_in[0];
    const int*   labels = (const int*)d_in[1];
    const float* lut    = (const float*)d_in[2];
    const float* cq     = (const float*)d_in[3];
    const float* rel    = (const float*)d_in[4];
    float* out = (float*)d_out;

    // workspace layout: proj [N_ROWS * C_COLS] fp32 (172.6 MB), then row_loss [N_ROWS]
    float* proj = (float*)d_ws;
    float* row_loss = proj + (size_t)N_ROWS * C_COLS;

    dim3 gemm_grid((C_COLS + BN - 1) / BN, N_ROWS / BM);
    gemm_proj<<<gemm_grid, 256, 0, stream>>>(inputs, lut, cq, rel, proj);
    row_loss_kernel<<<N_ROWS, 256, 0, stream>>>(proj, labels, row_loss);
    final_reduce<<<1, 256, 0, stream>>>(row_loss, out);
}

// Round 2
// 227.137 us; speedup vs baseline: 2.9510x; 2.9510x over previous
//
#include <hip/hip_runtime.h>
#include <math.h>

#define N_ROWS 4096
#define DIM    256
#define P_SZ   5532
#define Q_SZ   5000
#define C_COLS 10532            // P+Q
#define NV4    (C_COLS/4)       // 2633 exact
#define K_SEL  701              // HARD_NUM + 1
#define SCALAR 30.0f

typedef __attribute__((ext_vector_type(8))) short   short8;
typedef __attribute__((ext_vector_type(4))) float   float4_t;
typedef __attribute__((ext_vector_type(4))) unsigned short ushort4_t;

// ---------------- helpers ----------------
__device__ __forceinline__ unsigned short f2bf(float f) {   // fp32 -> bf16 RNE
    unsigned u = __float_as_uint(f);
    unsigned r = u + 0x7FFFu + ((u >> 16) & 1u);
    return (unsigned short)(r >> 16);
}
__device__ __forceinline__ unsigned f2key(float f) {        // order-preserving key
    unsigned b = __float_as_uint(f);
    return (b & 0x80000000u) ? ~b : (b | 0x80000000u);
}
__device__ __forceinline__ float key2f(unsigned key) {
    unsigned b = (key & 0x80000000u) ? (key & 0x7FFFFFFFu) : ~key;
    return __uint_as_float(b);
}

// counts in bins owned by HIGHER-tid threads (wave shfl suffix scan, no serial chain)
__device__ __forceinline__ unsigned suffix_above(unsigned s, int lane, int wid,
                                                 unsigned* wsum) {
    unsigned incl = s;
    #pragma unroll
    for (int off = 1; off < 64; off <<= 1) {
        unsigned v = __shfl_down(incl, off, 64);
        if (lane + off < 64) incl += v;
    }
    unsigned wtot = __shfl(incl, 0, 64);
    if (lane == 0) wsum[wid] = wtot;
    __syncthreads();
    unsigned tail = 0;
    for (int w = wid + 1; w < 4; ++w) tail += wsum[w];
    return tail + (incl - s);
}

// ---------------- bf16 MFMA GEMM: proj = (inputs @ table^T) * rel ----------------
#define BM 128
#define BN 128
#define BK 64

__global__ __launch_bounds__(256) void gemm_proj(
    const float* __restrict__ inputs, const float* __restrict__ lut,
    const float* __restrict__ cq, const float* __restrict__ rel,
    float* __restrict__ proj)
{
    // swizzled bf16 tiles: elem (r,k) at byte r*128 + ((k*2) ^ ((r&7)<<4))
    __shared__ __align__(16) unsigned short At[BM * BK];
    __shared__ __align__(16) unsigned short Bt[BN * BK];

    const int tid  = threadIdx.x;
    const int lane = tid & 63, wid = tid >> 6;
    const int wm = wid >> 1, wn = wid & 1;          // 2x2 waves of 64x64
    const int row0 = blockIdx.y * BM;
    const int col0 = blockIdx.x * BN;

    float4_t acc[4][4];
    #pragma unroll
    for (int i = 0; i < 4; ++i)
        #pragma unroll
        for (int j = 0; j < 4; ++j)
            acc[i][j] = (float4_t){0.f, 0.f, 0.f, 0.f};

    for (int k0 = 0; k0 < DIM; k0 += BK) {
        // stage A: 128x64 elems = 2048 float4 granules, 8 per thread
        #pragma unroll
        for (int it = 0; it < 8; ++it) {
            const int g  = it * 256 + tid;
            const int r  = g >> 4;                  // 0..127
            const int kq = (g & 15) << 2;           // 0..60 step 4
            const float4_t v = *(const float4_t*)&inputs[(size_t)(row0 + r) * DIM + k0 + kq];
            ushort4_t h = { f2bf(v.x), f2bf(v.y), f2bf(v.z), f2bf(v.w) };
            const unsigned byte = (unsigned)(r * 128 + ((kq * 2) ^ ((r & 7) << 4)));
            *(ushort4_t*)((char*)At + byte) = h;
        }
        // stage B (table = [lut; cq], zero-fill past C_COLS)
        #pragma unroll
        for (int it = 0; it < 8; ++it) {
            const int g  = it * 256 + tid;
            const int r  = g >> 4;
            const int kq = (g & 15) << 2;
            const int gc = col0 + r;
            float4_t v = (float4_t){0.f, 0.f, 0.f, 0.f};
            if (gc < C_COLS) {
                const float* src = (gc < P_SZ) ? lut + (size_t)gc * DIM
                                               : cq  + (size_t)(gc - P_SZ) * DIM;
                v = *(const float4_t*)&src[k0 + kq];
            }
            ushort4_t h = { f2bf(v.x), f2bf(v.y), f2bf(v.z), f2bf(v.w) };
            const unsigned byte = (unsigned)(r * 128 + ((kq * 2) ^ ((r & 7) << 4)));
            *(ushort4_t*)((char*)Bt + byte) = h;
        }
        __syncthreads();

        #pragma unroll
        for (int kk = 0; kk < 2; ++kk) {            // two 16x16x32 K-steps
            const int krow = lane & 15;
            const int kb   = kk * 64 + ((lane >> 4) << 4);   // byte offset along k
            short8 af[4], bfr[4];
            #pragma unroll
            for (int i = 0; i < 4; ++i) {
                const int r = wm * 64 + i * 16 + krow;
                af[i] = *(const short8*)((const char*)At + (r * 128 + (kb ^ ((r & 7) << 4))));
            }
            #pragma unroll
            for (int j = 0; j < 4; ++j) {
                const int r = wn * 64 + j * 16 + krow;
                bfr[j] = *(const short8*)((const char*)Bt + (r * 128 + (kb ^ ((r & 7) << 4))));
            }
            #pragma unroll
            for (int i = 0; i < 4; ++i)
                #pragma unroll
                for (int j = 0; j < 4; ++j)
                    acc[i][j] = __builtin_amdgcn_mfma_f32_16x16x32_bf16(af[i], bfr[j], acc[i][j], 0, 0, 0);
        }
        __syncthreads();
    }

    // epilogue: C frag layout col=lane&15, row=(lane>>4)*4+rr  [m89]
    const int lr = (lane >> 4) << 2;
    const int lc = lane & 15;
    #pragma unroll
    for (int j = 0; j < 4; ++j) {
        const int col = col0 + wn * 64 + j * 16 + lc;
        if (col >= C_COLS) continue;
        const float rl = rel[col];
        #pragma unroll
        for (int i = 0; i < 4; ++i) {
            const int row = row0 + wm * 64 + i * 16 + lr;
            #pragma unroll
            for (int rr = 0; rr < 4; ++rr)
                proj[(size_t)(row + rr) * C_COLS + col] = acc[i][j][rr] * rl;
        }
    }
}

// ---------------- per-row: 3-pass radix select + masked logsumexp ----------------
__global__ __launch_bounds__(256) void row_loss_kernel(
    const float* __restrict__ proj, const int* __restrict__ labels,
    float* __restrict__ row_loss)
{
    __shared__ __align__(16) float vals[C_COLS];    // 42128 B
    __shared__ unsigned hist[2048];                 // 8 KB
    __shared__ unsigned wsum[4];
    __shared__ float wred[4];
    __shared__ unsigned sel_b, sel_k;

    const int tid = threadIdx.x, lane = tid & 63, wid = tid >> 6;
    const int row = blockIdx.x;
    const float* prow = proj + (size_t)row * C_COLS;

    // clear hist
    for (int i = tid; i < 2048; i += 256) hist[i] = 0;
    __syncthreads();

    // load + row max + pass-1 histogram (key bits [31:21])
    float m = -INFINITY;
    for (int g = tid; g < NV4; g += 256) {
        const float4_t v = *(const float4_t*)&prow[g * 4];
        #pragma unroll
        for (int e = 0; e < 4; ++e) {
            const float f = v[e];
            vals[g * 4 + e] = f;
            m = fmaxf(m, f);
            atomicAdd(&hist[f2key(f) >> 21], 1u);
        }
    }
    #pragma unroll
    for (int off = 1; off < 64; off <<= 1) {
        const float t = __shfl_down(m, off, 64);
        if (lane + off < 64) m = fmaxf(m, t);
    }
    if (lane == 0) wred[wid] = m;
    __syncthreads();
    m = fmaxf(fmaxf(wred[0], wred[1]), fmaxf(wred[2], wred[3]));

    unsigned k = K_SEL;

    // ---- pass 1 select: 2048 bins, 8 per thread
    {
        unsigned s = 0;
        #pragma unroll
        for (int b = 0; b < 8; ++b) s += hist[tid * 8 + b];
        unsigned cum = suffix_above(s, lane, wid, wsum);
        #pragma unroll
        for (int b = 7; b >= 0; --b) {
            const unsigned c = hist[tid * 8 + b];
            if (cum < k && cum + c >= k) { sel_b = (unsigned)(tid * 8 + b); sel_k = k - cum; }
            cum += c;
        }
    }
    __syncthreads();
    const unsigned b1 = sel_b; k = sel_k;
    __syncthreads();

    // ---- pass 2: bins = key bits [20:10] among prefix-matching elems
    for (int i = tid; i < 2048; i += 256) hist[i] = 0;
    __syncthreads();
    for (int g = tid; g < NV4; g += 256) {
        const float4_t v = *(const float4_t*)&vals[g * 4];
        #pragma unroll
        for (int e = 0; e < 4; ++e) {
            const unsigned key = f2key(v[e]);
            if ((key >> 21) == b1) atomicAdd(&hist[(key >> 10) & 0x7FFu], 1u);
        }
    }
    __syncthreads();
    {
        unsigned s = 0;
        #pragma unroll
        for (int b = 0; b < 8; ++b) s += hist[tid * 8 + b];
        unsigned cum = suffix_above(s, lane, wid, wsum);
        #pragma unroll
        for (int b = 7; b >= 0; --b) {
            const unsigned c = hist[tid * 8 + b];
            if (cum < k && cum + c >= k) { sel_b = (unsigned)(tid * 8 + b); sel_k = k - cum; }
            cum += c;
        }
    }
    __syncthreads();
    const unsigned prefix22 = (b1 << 11) | sel_b; k = sel_k;
    __syncthreads();

    // ---- pass 3: bins = key bits [9:0]
    for (int i = tid; i < 1024; i += 256) hist[i] = 0;
    __syncthreads();
    for (int g = tid; g < NV4; g += 256) {
        const float4_t v = *(const float4_t*)&vals[g * 4];
        #pragma unroll
        for (int e = 0; e < 4; ++e) {
            const unsigned key = f2key(v[e]);
            if ((key >> 10) == prefix22) atomicAdd(&hist[key & 0x3FFu], 1u);
        }
    }
    __syncthreads();
    {
        unsigned s = 0;
        #pragma unroll
        for (int b = 0; b < 4; ++b) s += hist[tid * 4 + b];
        unsigned cum = suffix_above(s, lane, wid, wsum);
        #pragma unroll
        for (int b = 3; b >= 0; --b) {
            const unsigned c = hist[tid * 4 + b];
            if (cum < k && cum + c >= k) { sel_b = (unsigned)(tid * 4 + b); }
            cum += c;
        }
    }
    __syncthreads();
    const float boundary = key2f((prefix22 << 10) | sel_b);

    // ---- masked sum of exp
    const float c2 = SCALAR * 1.4426950408889634f;   // use exp2
    float s = 0.f;
    for (int g = tid; g < NV4; g += 256) {
        const float4_t v = *(const float4_t*)&vals[g * 4];
        #pragma unroll
        for (int e = 0; e < 4; ++e)
            if (v[e] >= boundary) s += exp2f(c2 * (v[e] - m));
    }
    #pragma unroll
    for (int off = 1; off < 64; off <<= 1) {
        const float t = __shfl_down(s, off, 64);
        if (lane + off < 64) s += t;
    }
    if (lane == 0) wred[wid] = s;
    __syncthreads();

    if (tid == 0) {
        float total = wred[0] + wred[1] + wred[2] + wred[3];
        const int lab = labels[row];
        const float pl = vals[lab];                  // label column, always unmasked
        if (pl < boundary) total += exp2f(c2 * (pl - m));
        row_loss[row] = SCALAR * m + logf(total) - SCALAR * pl;
    }
}

// ---------------- final mean ----------------
__global__ __launch_bounds__(256) void final_reduce(
    const float* __restrict__ row_loss, float* __restrict__ out)
{
    __shared__ float wred[4];
    const int tid = threadIdx.x, lane = tid & 63, wid = tid >> 6;
    float s = 0.f;
    for (int i = tid; i < N_ROWS; i += 256) s += row_loss[i];
    #pragma unroll
    for (int off = 1; off < 64; off <<= 1) {
        const float t = __shfl_down(s, off, 64);
        if (lane + off < 64) s += t;
    }
    if (lane == 0) wred[wid] = s;
    __syncthreads();
    if (tid == 0) out[0] = (wred[0] + wred[1] + wred[2] + wred[3]) / (float)N_ROWS;
}

extern "C" void kernel_launch(void* const* d_in, const int* in_sizes, int n_in,
                              void* d_out, int out_size, void* d_ws, size_t ws_size,
                              hipStream_t stream) {
    const float* inputs = (const float*)d_in[0];
    const int*   labels = (const int*)d_in[1];
    const float* lut    = (const float*)d_in[2];
    const float* cq     = (const float*)d_in[3];
    const float* rel    = (const float*)d_in[4];
    float* out = (float*)d_out;

    float* proj     = (float*)d_ws;                          // 4096*10532 fp32
    float* row_loss = proj + (size_t)N_ROWS * C_COLS;

    dim3 gg((C_COLS + BN - 1) / BN, N_ROWS / BM);            // 83 x 32
    gemm_proj<<<gg, 256, 0, stream>>>(inputs, lut, cq, rel, proj);
    row_loss_kernel<<<N_ROWS, 256, 0, stream>>>(proj, labels, row_loss);
    final_reduce<<<1, 256, 0, stream>>>(row_loss, out);
}

// Round 3
// 115.388 us; speedup vs baseline: 5.8089x; 1.9685x over previous
//
#include <hip/hip_runtime.h>
#include <math.h>

#define N_ROWS 4096
#define DIM    256
#define P_SZ   5532
#define Q_SZ   5000
#define C_COLS 10532            // P+Q
#define TPAD   10624            // table rows padded to 83*128 (zero-filled)
#define PSTR   10560            // proj row stride in bf16 elems (mult of 8)
#define K_SEL  701              // HARD_NUM + 1
#define SCALAR 30.0f

typedef __attribute__((ext_vector_type(8))) short   short8;
typedef __attribute__((ext_vector_type(4))) float   float4_t;
typedef __attribute__((ext_vector_type(4))) unsigned short ushort4_t;
typedef __attribute__((ext_vector_type(8))) unsigned short ushort8_t;

// ---------------- helpers ----------------
__device__ __forceinline__ unsigned short f2bf(float f) {   // fp32 -> bf16 RNE
    unsigned u = __float_as_uint(f);
    unsigned r = u + 0x7FFFu + ((u >> 16) & 1u);
    return (unsigned short)(r >> 16);
}
__device__ __forceinline__ float bf2f(unsigned short u) {
    return __uint_as_float((unsigned)u << 16);
}
__device__ __forceinline__ unsigned key16(unsigned short u) { // order-preserving 16-bit key
    return (u & 0x8000u) ? (unsigned)(~u & 0xFFFFu) : (unsigned)(u | 0x8000u);
}
__device__ __forceinline__ float key2f16(unsigned key) {
    unsigned short b = (key & 0x8000u) ? (unsigned short)(key & 0x7FFFu)
                                       : (unsigned short)(~key & 0xFFFFu);
    return bf2f(b);
}
__device__ __forceinline__ void gload16(const void* g, void* l) {
    __builtin_amdgcn_global_load_lds(
        (const __attribute__((address_space(1))) unsigned int*)g,
        (__attribute__((address_space(3))) unsigned int*)l, 16, 0, 0);
}

// counts in bins owned by HIGHER-tid threads (wave shfl suffix scan)
__device__ __forceinline__ unsigned suffix_above(unsigned s, int lane, int wid,
                                                 unsigned* wsum) {
    unsigned incl = s;
    #pragma unroll
    for (int off = 1; off < 64; off <<= 1) {
        unsigned v = __shfl_down(incl, off, 64);
        if (lane + off < 64) incl += v;
    }
    unsigned wtot = __shfl(incl, 0, 64);
    if (lane == 0) wsum[wid] = wtot;
    __syncthreads();
    unsigned tail = 0;
    for (int w = wid + 1; w < 4; ++w) tail += wsum[w];
    return tail + (incl - s);
}

// ---------------- fp32 -> bf16 pre-conversion (inputs + padded table) ----------------
#define NIN_G  (N_ROWS * DIM / 4)       // 262144 float4 granules
#define NTAB_G (TPAD * DIM / 4)         // 679936

__global__ __launch_bounds__(256) void convert_bf16(
    const float* __restrict__ inputs, const float* __restrict__ lut,
    const float* __restrict__ cq, unsigned short* __restrict__ in_bf,
    unsigned short* __restrict__ tab_bf)
{
    const int g = blockIdx.x * 256 + threadIdx.x;
    if (g >= NIN_G + NTAB_G) return;
    float4_t v;
    unsigned short* dst;
    if (g < NIN_G) {
        v = *(const float4_t*)&inputs[(size_t)g * 4];
        dst = in_bf + (size_t)g * 4;
    } else {
        const int t = g - NIN_G;
        const int row = t >> 6;                 // /(DIM/4)
        const int c4  = (t & 63) * 4;
        if (row < P_SZ)        v = *(const float4_t*)&lut[(size_t)row * DIM + c4];
        else if (row < C_COLS) v = *(const float4_t*)&cq[(size_t)(row - P_SZ) * DIM + c4];
        else                   v = (float4_t){0.f, 0.f, 0.f, 0.f};
        dst = tab_bf + (size_t)t * 4;
    }
    ushort4_t h = { f2bf(v.x), f2bf(v.y), f2bf(v.z), f2bf(v.w) };
    *(ushort4_t*)dst = h;
}

// ---------------- bf16 MFMA GEMM: proj(bf16) = (in @ tab^T) * rel ----------------
#define NWG_X 83
#define NWG_Y 32
#define NWG   (NWG_X * NWG_Y)   // 2656, divisible by 8

__global__ __launch_bounds__(256) void gemm_proj(
    const unsigned short* __restrict__ in_bf,
    const unsigned short* __restrict__ tab_bf,
    const float* __restrict__ rel,
    unsigned short* __restrict__ proj)
{
    // swizzled bf16 tiles: elem (r,k) at byte r*128 + ((k*2) ^ ((r&7)<<4))
    __shared__ __align__(16) unsigned short At[128 * 64];
    __shared__ __align__(16) unsigned short Bt[128 * 64];

    const int tid  = threadIdx.x;
    const int lane = tid & 63, wid = tid >> 6;
    const int wm = wid >> 1, wn = wid & 1;

    // XCD-bijective swizzle, col-major decode: each XCD chunk keeps full A in L2
    const int phys = blockIdx.x;
    const int wg   = (phys & 7) * (NWG / 8) + (phys >> 3);
    const int bx   = wg >> 5;               // 0..82 col-block
    const int by   = wg & 31;               // 0..31 row-block
    const int row0 = by * 128, col0 = bx * 128;

    float4_t acc[4][4];
    #pragma unroll
    for (int i = 0; i < 4; ++i)
        #pragma unroll
        for (int j = 0; j < 4; ++j)
            acc[i][j] = (float4_t){0.f, 0.f, 0.f, 0.f};

    for (int k0 = 0; k0 < DIM; k0 += 64) {
        // stage: linear LDS dest + inverse-swizzled global source (16B granules)
        #pragma unroll
        for (int it = 0; it < 4; ++it) {
            const int g  = it * 256 + tid;       // granule: LDS byte = g*16
            const int r  = g >> 3;               // 0..127
            const int kb = ((g & 7) * 16) ^ ((r & 7) << 4);   // src byte within row
            gload16(in_bf  + (size_t)(row0 + r) * DIM + k0 + (kb >> 1),
                    (char*)At + g * 16);
            gload16(tab_bf + (size_t)(col0 + r) * DIM + k0 + (kb >> 1),
                    (char*)Bt + g * 16);
        }
        __syncthreads();

        #pragma unroll
        for (int kk = 0; kk < 2; ++kk) {
            const int krow = lane & 15;
            const int kb   = kk * 64 + ((lane >> 4) << 4);
            short8 af[4], bfr[4];
            #pragma unroll
            for (int i = 0; i < 4; ++i) {
                const int r = wm * 64 + i * 16 + krow;
                af[i] = *(const short8*)((const char*)At + (r * 128 + (kb ^ ((r & 7) << 4))));
            }
            #pragma unroll
            for (int j = 0; j < 4; ++j) {
                const int r = wn * 64 + j * 16 + krow;
                bfr[j] = *(const short8*)((const char*)Bt + (r * 128 + (kb ^ ((r & 7) << 4))));
            }
            #pragma unroll
            for (int i = 0; i < 4; ++i)
                #pragma unroll
                for (int j = 0; j < 4; ++j)
                    acc[i][j] = __builtin_amdgcn_mfma_f32_16x16x32_bf16(af[i], bfr[j], acc[i][j], 0, 0, 0);
        }
        __syncthreads();
    }

    // epilogue: C layout col=lane&15, row=(lane>>4)*4+rr  [m89]
    const int lr = (lane >> 4) << 2;
    const int lc = lane & 15;
    #pragma unroll
    for (int j = 0; j < 4; ++j) {
        const int col = col0 + wn * 64 + j * 16 + lc;
        if (col >= PSTR) continue;
        const bool pad = (col >= C_COLS);
        const float rl = pad ? 0.f : rel[col];
        #pragma unroll
        for (int i = 0; i < 4; ++i) {
            const int row = row0 + wm * 64 + i * 16 + lr;
            #pragma unroll
            for (int rr = 0; rr < 4; ++rr)
                proj[(size_t)(row + rr) * PSTR + col] =
                    pad ? (unsigned short)0xFF80u            // -inf bf16
                        : f2bf(acc[i][j][rr] * rl);
        }
    }
}

// ---------------- per-row: 2-pass radix select (16-bit keys) + masked LSE ----------------
__global__ __launch_bounds__(256) void row_loss_kernel(
    const unsigned short* __restrict__ proj, const int* __restrict__ labels,
    float* __restrict__ row_loss)
{
    __shared__ __align__(16) unsigned short vals[PSTR];   // 21120 B
    __shared__ unsigned hist[2048];                        // 8 KB
    __shared__ unsigned wsum[4];
    __shared__ unsigned wred[4];
    __shared__ float fred[4];
    __shared__ unsigned sel_b, sel_k;

    const int tid = threadIdx.x, lane = tid & 63, wid = tid >> 6;
    const int row = blockIdx.x;
    const ushort8_t* prow = (const ushort8_t*)(proj + (size_t)row * PSTR);

    for (int i = tid; i < 2048; i += 256) hist[i] = 0;
    __syncthreads();

    // load + max(key) + pass-1 histogram on key bits [15:5]
    unsigned mkey = 0;
    for (int g = tid; g < PSTR / 8; g += 256) {           // 1320 granules
        const ushort8_t v = prow[g];
        *(ushort8_t*)&vals[g * 8] = v;
        #pragma unroll
        for (int e = 0; e < 8; ++e) {
            const unsigned key = key16(v[e]);
            mkey = max(mkey, key);
            atomicAdd(&hist[key >> 5], 1u);
        }
    }
    #pragma unroll
    for (int off = 1; off < 64; off <<= 1) {
        const unsigned t = __shfl_down(mkey, off, 64);
        if (lane + off < 64) mkey = max(mkey, t);
    }
    if (lane == 0) wred[wid] = mkey;
    __syncthreads();
    mkey = max(max(wred[0], wred[1]), max(wred[2], wred[3]));
    const float m = key2f16(mkey);

    unsigned k = K_SEL;

    // ---- pass 1: 2048 bins, 8 per thread
    {
        unsigned s = 0;
        #pragma unroll
        for (int b = 0; b < 8; ++b) s += hist[tid * 8 + b];
        unsigned cum = suffix_above(s, lane, wid, wsum);
        #pragma unroll
        for (int b = 7; b >= 0; --b) {
            const unsigned c = hist[tid * 8 + b];
            if (cum < k && cum + c >= k) { sel_b = (unsigned)(tid * 8 + b); sel_k = k - cum; }
            cum += c;
        }
    }
    __syncthreads();
    const unsigned b1 = sel_b; k = sel_k;
    if (tid < 32) hist[tid] = 0;
    __syncthreads();

    // ---- pass 2: 32 bins = key bits [4:0] among prefix matches
    for (int g = tid; g < PSTR / 8; g += 256) {
        const ushort8_t v = *(const ushort8_t*)&vals[g * 8];
        #pragma unroll
        for (int e = 0; e < 8; ++e) {
            const unsigned key = key16(v[e]);
            if ((key >> 5) == b1) atomicAdd(&hist[key & 31u], 1u);
        }
    }
    __syncthreads();
    if (wid == 0) {
        const unsigned c = (lane < 32) ? hist[lane] : 0u;
        unsigned incl = c;
        #pragma unroll
        for (int off = 1; off < 64; off <<= 1) {
            const unsigned t = __shfl_down(incl, off, 64);
            if (lane + off < 64) incl += t;
        }
        const unsigned above = incl - c;
        if (lane < 32 && above < k && above + c >= k) sel_b = (unsigned)lane;
    }
    __syncthreads();
    const unsigned bkey = (b1 << 5) | sel_b;

    // ---- masked sum of exp (key-domain compare)
    const float c2 = SCALAR * 1.4426950408889634f;
    float s = 0.f;
    for (int g = tid; g < PSTR / 8; g += 256) {
        const ushort8_t v = *(const ushort8_t*)&vals[g * 8];
        #pragma unroll
        for (int e = 0; e < 8; ++e)
            if (key16(v[e]) >= bkey) s += exp2f(c2 * (bf2f(v[e]) - m));
    }
    #pragma unroll
    for (int off = 1; off < 64; off <<= 1) {
        const float t = __shfl_down(s, off, 64);
        if (lane + off < 64) s += t;
    }
    if (lane == 0) fred[wid] = s;
    __syncthreads();

    if (tid == 0) {
        float total = fred[0] + fred[1] + fred[2] + fred[3];
        const unsigned short ul = vals[labels[row]];      // label < P_SZ < PSTR
        const float pl = bf2f(ul);
        if (key16(ul) < bkey) total += exp2f(c2 * (pl - m));
        row_loss[row] = SCALAR * m + logf(total) - SCALAR * pl;
    }
}

// ---------------- final mean ----------------
__global__ __launch_bounds__(256) void final_reduce(
    const float* __restrict__ row_loss, float* __restrict__ out)
{
    __shared__ float fred[4];
    const int tid = threadIdx.x, lane = tid & 63, wid = tid >> 6;
    float s = 0.f;
    for (int i = tid; i < N_ROWS; i += 256) s += row_loss[i];
    #pragma unroll
    for (int off = 1; off < 64; off <<= 1) {
        const float t = __shfl_down(s, off, 64);
        if (lane + off < 64) s += t;
    }
    if (lane == 0) fred[wid] = s;
    __syncthreads();
    if (tid == 0) out[0] = (fred[0] + fred[1] + fred[2] + fred[3]) / (float)N_ROWS;
}

extern "C" void kernel_launch(void* const* d_in, const int* in_sizes, int n_in,
                              void* d_out, int out_size, void* d_ws, size_t ws_size,
                              hipStream_t stream) {
    const float* inputs = (const float*)d_in[0];
    const int*   labels = (const int*)d_in[1];
    const float* lut    = (const float*)d_in[2];
    const float* cq     = (const float*)d_in[3];
    const float* rel    = (const float*)d_in[4];
    float* out = (float*)d_out;

    // ws: in_bf [4096*256] | tab_bf [10624*256] | proj [4096*10560] bf16 | row_loss
    unsigned short* in_bf  = (unsigned short*)d_ws;
    unsigned short* tab_bf = in_bf  + (size_t)N_ROWS * DIM;
    unsigned short* proj   = tab_bf + (size_t)TPAD * DIM;
    float* rl_buf = (float*)(proj + (size_t)N_ROWS * PSTR);

    convert_bf16<<<(NIN_G + NTAB_G) / 256, 256, 0, stream>>>(inputs, lut, cq, in_bf, tab_bf);
    gemm_proj<<<NWG, 256, 0, stream>>>(in_bf, tab_bf, rel, proj);
    row_loss_kernel<<<N_ROWS, 256, 0, stream>>>(proj, labels, rl_buf);
    final_reduce<<<1, 256, 0, stream>>>(rl_buf, out);
}